// Round 7
// baseline (735.025 us; speedup 1.0000x reference)
//
#include <hip/hip_runtime.h>
#include <math.h>

#define HH 19
#define NB 1024
#define TT 2048

typedef float v2f __attribute__((ext_vector_type(2)));
typedef unsigned u2 __attribute__((ext_vector_type(2)));
typedef _Float16 v2h __attribute__((ext_vector_type(2)));

__device__ __forceinline__ unsigned rlu(unsigned v, int l) {
  return (unsigned)__builtin_amdgcn_readlane((int)v, l);
}
__device__ __forceinline__ float frcp(float v) {
  return __builtin_amdgcn_rcpf(v);
}
__device__ __forceinline__ float fexp2(float v) {
#if __has_builtin(__builtin_amdgcn_exp2f)
  return __builtin_amdgcn_exp2f(v);
#else
  return exp2f(v);
#endif
}
__device__ __forceinline__ v2f vfma(v2f a, v2f b, v2f c) {
#if __has_builtin(__builtin_elementwise_fma)
  return __builtin_elementwise_fma(a, b, c);
#else
  v2f r; r.x = fmaf(a.x, b.x, c.x); r.y = fmaf(a.y, b.y, c.y); return r;
#endif
}

// v_dot2_f32_f16: a.x*b.x + a.y*b.y + c with f32 accumulate (full rate)
#if __has_builtin(__builtin_amdgcn_fdot2)
#define HAVE_DOT2 1
__device__ __forceinline__ float dot2h(v2h w, unsigned packed, float acc) {
  return __builtin_amdgcn_fdot2(w, __builtin_bit_cast(v2h, packed), acc, false);
}
#else
#define HAVE_DOT2 0
__device__ __forceinline__ float dot2h(v2h w, unsigned packed, float acc) {
  const float fl = (float)__builtin_bit_cast(_Float16, (unsigned short)(packed & 0xffffu));
  const float fh = (float)__builtin_bit_cast(_Float16, (unsigned short)(packed >> 16));
  return fmaf((float)w.x, fl, fmaf((float)w.y, fh, acc));
}
#endif

// halves-broadcast via permlane32_swap builtin (proven in round 6)
#if __has_builtin(__builtin_amdgcn_permlane32_swap)
#define HAVE_PLS 1
__device__ __forceinline__ u2 pls(float x) {
  unsigned u = __float_as_uint(x);
  return __builtin_amdgcn_permlane32_swap(u, u, false, false);
}
#endif

// 57-lane spread, one gate-row per lane:
//   lanes 0-18 r-rows (h_i owners) | 19-31 z-rows 19-31 | 32-50 n-rows | 51-56 z-rows 32-37
// r_i->n-lane, n_i->h-lane via permlane32_swap; z_i->h-lane via ds_bpermute.
// h-dot & out-proj via v_dot2_f32_f16 (f16 inputs, f32 accum). x-dot f32,
// software-pipelined one step ahead to fill the recurrence chain's bubbles.
__global__ void __launch_bounds__(64)
__attribute__((amdgpu_waves_per_eu(1, 1)))
gru57_v3(const float* __restrict__ x, const float* __restrict__ Wih,
         const float* __restrict__ Whh, const float* __restrict__ bih,
         const float* __restrict__ bhh, const float* __restrict__ Wout,
         const float* __restrict__ bout, float* __restrict__ out)
{
  const int b = blockIdx.x;
  const int lane = threadIdx.x;

  const float L2E = 1.4426950408889634f;   // log2(e)

  int row;
  if (lane < 32)      row = lane;
  else if (lane < 51) row = lane + 6;
  else if (lane < 57) row = lane - 19;
  else                row = 37;
  const bool isn = (row >= 2 * HH);
  const float scale = isn ? (2.0f * L2E) : L2E;

  // x-side weights f32 pairs; h-side + Wout as f16 pairs (dot2 inputs)
  v2f wx2[10];
  v2h wh16[10], wo16[10];
#pragma unroll
  for (int j = 0; j < 10; ++j) {
    const int k0 = 2 * j, k1 = 2 * j + 1;
    wx2[j].x = Wih[row * HH + k0] * scale;
    wx2[j].y = (k1 < HH) ? Wih[row * HH + k1] * scale : 0.0f;
    wh16[j].x = (_Float16)(Whh[row * HH + k0] * scale);
    wh16[j].y = (_Float16)((k1 < HH) ? Whh[row * HH + k1] * scale : 0.0f);
    wo16[j].x = (_Float16)Wout[k0];
    wo16[j].y = (_Float16)((k1 < HH) ? Wout[k1] : 0.0f);
  }
  const float bxv = bih[row] * scale, bhv = bhh[row] * scale;
  const float ax0 = isn ? bxv : (bxv + bhv);  // n keeps h-bias inside r*(...)
  const float ah0 = isn ? bhv : 0.0f;
  const float bo  = bout[0];

  // z-gather source (h-lane i reads z_i), byte address
  const int il = lane < HH ? lane : HH - 1;
  const int zaddr = ((il < 13) ? (19 + il) : (38 + il)) * 4;

#if HAVE_PLS
  bool loIsX;
  {
    unsigned l = (unsigned)lane;
    u2 pr = __builtin_amdgcn_permlane32_swap(l, l, false, false);
    loIsX = ((unsigned)__builtin_amdgcn_readlane((int)pr.x, 32) < 32u);
  }
#else
  const int loaddr = (lane & 31) * 4;
  const int hiaddr = ((lane & 31) | 32) * 4;
#endif

  float h = 0.0f;          // lane i (<19) owns h_i (f32 always)
  unsigned shp[10];        // wave-uniform h as packed f16 pairs (SGPRs)
#pragma unroll
  for (int j = 0; j < 10; ++j) shp[j] = 0u;

  // laundered zero keeps x loads in the vector pipe (SGPR file is tight)
  int vz;
  asm("v_mov_b32 %0, 0" : "=v"(vz));

  v2f xA[10], xB[10], xC[10], xD[10];
  xA[9].y = 0.0f; xB[9].y = 0.0f; xC[9].y = 0.0f; xD[9].y = 0.0f;

#define LOADROW(dst, trow) do {                                         \
    const float* _p = x + ((size_t)(trow) * NB + b) * HH + vz;          \
    _Pragma("unroll")                                                   \
    for (int _j = 0; _j < 9; ++_j) {                                    \
      dst[_j].x = _p[2 * _j];                                           \
      dst[_j].y = _p[2 * _j + 1];                                       \
    }                                                                   \
    dst[9].x = _p[18];                                                  \
  } while (0)

  // f32 x-dot -> scalar pre-activation for a FUTURE step
#define XDOT(buf, dstvar) do {                                          \
    v2f _aA = {ax0, 0.0f}, _aB = {0.0f, 0.0f};                          \
    _Pragma("unroll")                                                   \
    for (int _j = 0; _j < 5; ++_j)  _aA = vfma(buf[_j], wx2[_j], _aA);  \
    _Pragma("unroll")                                                   \
    for (int _j = 5; _j < 10; ++_j) _aB = vfma(buf[_j], wx2[_j], _aB);  \
    const v2f _s = _aA + _aB;                                           \
    dstvar = _s.x + _s.y;                                               \
  } while (0)

#if HAVE_PLS
#define LOBCAST(val, dst) do { u2 _s = pls(val);                        \
    dst = __uint_as_float(loIsX ? _s.x : _s.y); } while (0)
#define HIBCAST(val, dst) do { u2 _s = pls(val);                        \
    dst = __uint_as_float(loIsX ? _s.y : _s.x); } while (0)
#else
#define LOBCAST(val, dst) dst = __uint_as_float((unsigned)              \
    __builtin_amdgcn_ds_bpermute(loaddr, (int)__float_as_uint(val)))
#define HIBCAST(val, dst) dst = __uint_as_float((unsigned)              \
    __builtin_amdgcn_ds_bpermute(hiaddr, (int)__float_as_uint(val)))
#endif

  LOADROW(xA, 0); LOADROW(xB, 1); LOADROW(xC, 2); LOADROW(xD, 3);
  float prex;                 // pipelined x·W pre-activation for step t
  XDOT(xA, prex);

  // BODY(t): consume prex(t); fill chain bubbles with XDOT(t+1) + LOADROW(t+4)
#define BODY(tcur, nbuf, lbuf) do {                                     \
    /* chain head: h-dot via dot2 (uses shp from previous step) */      \
    float ahA = ah0, ahB = 0.0f;                                        \
    _Pragma("unroll")                                                   \
    for (int _j = 0; _j < 5; ++_j)  ahA = dot2h(wh16[_j], shp[_j], ahA);\
    _Pragma("unroll")                                                   \
    for (int _j = 5; _j < 10; ++_j) ahB = dot2h(wh16[_j], shp[_j], ahB);\
    /* independent filler inside the chain's latency window */          \
    float prexN;                                                        \
    XDOT(nbuf, prexN);                                                  \
    { const int _tl = ((tcur) + 4 < TT) ? (tcur) + 4 : TT - 1;          \
      LOADROW(lbuf, _tl); }                                             \
    /* chain continues */                                               \
    const float preh = ahA + ahB;                                       \
    const float pre  = prex + preh;                                     \
    const float sig  = frcp(1.0f + fexp2(-pre));                        \
    const int zzi = __builtin_amdgcn_ds_bpermute(                       \
        zaddr, (int)__float_as_uint(sig));                              \
    float rr; LOBCAST(sig, rr);                                         \
    const float npre = fmaf(rr, preh, prex);                            \
    const float nn = fmaf(-2.0f, frcp(fexp2(npre) + 1.0f), 1.0f);       \
    float nh; HIBCAST(nn, nh);                                          \
    const float zz = __uint_as_float((unsigned)zzi);                    \
    h = fmaf(zz, h - nh, nh);                                           \
    /* broadcast h as packed f16 pairs (readlane -> SALU pack) */       \
    const unsigned hb = (unsigned)__builtin_bit_cast(                   \
        unsigned short, (_Float16)h);                                   \
    _Pragma("unroll")                                                   \
    for (int _j = 0; _j < 9; ++_j)                                      \
      shp[_j] = rlu(hb, 2 * _j) | (rlu(hb, 2 * _j + 1) << 16);          \
    shp[9] = rlu(hb, 18);                                               \
    /* out-projection via dot2 */                                       \
    float oA = bo, oB = 0.0f;                                           \
    _Pragma("unroll")                                                   \
    for (int _j = 0; _j < 5; ++_j)  oA = dot2h(wo16[_j], shp[_j], oA);  \
    _Pragma("unroll")                                                   \
    for (int _j = 5; _j < 10; ++_j) oB = dot2h(wo16[_j], shp[_j], oB);  \
    if (lane == 0) out[(size_t)(tcur) * NB + b] = oA + oB;              \
    prex = prexN;                                                       \
  } while (0)

  for (int t = 0; t < TT; t += 4) {
    BODY(t + 0, xB, xA);
    BODY(t + 1, xC, xB);
    BODY(t + 2, xD, xC);
    BODY(t + 3, xA, xD);
  }

#undef LOADROW
#undef XDOT
#undef BODY
#undef LOBCAST
#undef HIBCAST
}

extern "C" void kernel_launch(void* const* d_in, const int* in_sizes, int n_in,
                              void* d_out, int out_size, void* d_ws, size_t ws_size,
                              hipStream_t stream) {
  const float* x    = (const float*)d_in[0];
  const float* Wih  = (const float*)d_in[1];
  const float* Whh  = (const float*)d_in[2];
  const float* bih  = (const float*)d_in[3];
  const float* bhh  = (const float*)d_in[4];
  const float* Wout = (const float*)d_in[5];
  const float* bout = (const float*)d_in[6];
  float* out = (float*)d_out;

  gru57_v3<<<dim3(NB), dim3(64), 0, stream>>>(
      x, Wih, Whh, bih, bhh, Wout, bout, out);
}

// Round 8
// 555.227 us; speedup vs baseline: 1.3238x; 1.3238x over previous
//
#include <hip/hip_runtime.h>
#include <math.h>

#define HH 19
#define NB 1024
#define TT 2048

typedef float v2f __attribute__((ext_vector_type(2)));
typedef unsigned u2 __attribute__((ext_vector_type(2)));

// readlane: VGPR -> wave-uniform SGPR; ignores exec mask
__device__ __forceinline__ float rlf(float v, int l) {
  return __uint_as_float(__builtin_amdgcn_readlane(__float_as_uint(v), l));
}
__device__ __forceinline__ float frcp(float v) {
  return __builtin_amdgcn_rcpf(v);
}
__device__ __forceinline__ float fexp2(float v) {
#if __has_builtin(__builtin_amdgcn_exp2f)
  return __builtin_amdgcn_exp2f(v);
#else
  return exp2f(v);
#endif
}
__device__ __forceinline__ v2f vfma(v2f a, v2f b, v2f c) {
#if __has_builtin(__builtin_elementwise_fma)
  return __builtin_elementwise_fma(a, b, c);
#else
  v2f r; r.x = fmaf(a.x, b.x, c.x); r.y = fmaf(a.y, b.y, c.y); return r;
#endif
}

// halves-broadcast via permlane32_swap builtin (proven round 6)
#if __has_builtin(__builtin_amdgcn_permlane32_swap)
#define HAVE_PLS 1
__device__ __forceinline__ u2 pls(float x) {
  unsigned u = __float_as_uint(x);
  return __builtin_amdgcn_permlane32_swap(u, u, false, false);
}
#else
#define HAVE_PLS 0
#endif

// 57-lane spread, one gate-row per lane (round-6 structure):
//   lanes 0-18 r-rows (h_i owners) | 19-31 z-rows 19-31 | 32-50 n-rows | 51-56 z-rows 32-37
// r_i->n-lane, n_i->h-lane via permlane32_swap; z_i->h-lane via ds_bpermute.
// NEW: x staging is ONE lane-parallel global_load_dword per step (lane k<19
// loads x[t+4][b][k]) -> <=4 outstanding VMEM, clean vmcnt(N) waits (the old
// 4x19 uniform-load scheme kept 76 outstanding, over the 63 vmcnt ceiling).
__global__ void __launch_bounds__(64)
__attribute__((amdgpu_waves_per_eu(1, 1)))
gru57_v4(const float* __restrict__ x, const float* __restrict__ Wih,
         const float* __restrict__ Whh, const float* __restrict__ bih,
         const float* __restrict__ bhh, const float* __restrict__ Wout,
         const float* __restrict__ bout, float* __restrict__ out)
{
  const int b = blockIdx.x;
  const int lane = threadIdx.x;

  const float L2E = 1.4426950408889634f;   // log2(e)

  int row;
  if (lane < 32)      row = lane;
  else if (lane < 51) row = lane + 6;
  else if (lane < 57) row = lane - 19;
  else                row = 37;
  const bool isn = (row >= 2 * HH);
  const float scale = isn ? (2.0f * L2E) : L2E;

  // per-lane weight row (x-side, h-side) + uniform Wout, all f32 v2f
  v2f wx2[10], wh2[10], wo2[10];
#pragma unroll
  for (int j = 0; j < 10; ++j) {
    const int k0 = 2 * j, k1 = 2 * j + 1;
    wx2[j].x = Wih[row * HH + k0] * scale;
    wx2[j].y = (k1 < HH) ? Wih[row * HH + k1] * scale : 0.0f;
    wh2[j].x = Whh[row * HH + k0] * scale;
    wh2[j].y = (k1 < HH) ? Whh[row * HH + k1] * scale : 0.0f;
    wo2[j].x = Wout[k0];
    wo2[j].y = (k1 < HH) ? Wout[k1] : 0.0f;
  }
  const float bxv = bih[row] * scale, bhv = bhh[row] * scale;
  const float ax0 = isn ? bxv : (bxv + bhv);  // n keeps h-bias inside r*(...)
  const float ah0 = isn ? bhv : 0.0f;
  const float bo  = bout[0];

  // z-gather source (h-lane i reads z_i), byte address
  const int il = lane < HH ? lane : HH - 1;
  const int zaddr = ((il < 13) ? (19 + il) : (38 + il)) * 4;

#if HAVE_PLS
  bool loIsX;
  {
    unsigned l = (unsigned)lane;
    u2 pr = __builtin_amdgcn_permlane32_swap(l, l, false, false);
    loIsX = ((unsigned)__builtin_amdgcn_readlane((int)pr.x, 32) < 32u);
  }
#else
  const int loaddr = (lane & 31) * 4;
  const int hiaddr = ((lane & 31) | 32) * 4;
#endif

  float h = 0.0f;      // lane i (<19) owns h_i
  v2f sh2[10];         // wave-uniform h copy (readlane -> SGPR pairs)
#pragma unroll
  for (int j = 0; j < 10; ++j) { sh2[j].x = 0.0f; sh2[j].y = 0.0f; }

  // lane-parallel x staging: lane k (<19) holds x[trow][b][k] in one VGPR
  const int kx = lane < HH ? lane : HH - 1;
  const float* __restrict__ xbase = x + (size_t)b * HH + kx;

#define LOADX(dst, trow) do {                                           \
    dst = xbase[(size_t)(trow) * (NB * HH)];                            \
  } while (0)

  // broadcast a staged x row (VGPR across lanes 0-18) to SGPR v2f pairs
#define XBCAST(slot, xu) do {                                           \
    _Pragma("unroll")                                                   \
    for (int _j = 0; _j < 9; ++_j) {                                    \
      xu[_j].x = rlf(slot, 2 * _j);                                     \
      xu[_j].y = rlf(slot, 2 * _j + 1);                                 \
    }                                                                   \
    xu[9].x = rlf(slot, 18); xu[9].y = 0.0f;                            \
  } while (0)

  // x-dot for a future step: per-lane weights x uniform x row
#define XDOT(xu, dstvar) do {                                           \
    v2f _aA = {ax0, 0.0f}, _aB = {0.0f, 0.0f};                          \
    _Pragma("unroll")                                                   \
    for (int _j = 0; _j < 5; ++_j)  _aA = vfma(xu[_j], wx2[_j], _aA);   \
    _Pragma("unroll")                                                   \
    for (int _j = 5; _j < 10; ++_j) _aB = vfma(xu[_j], wx2[_j], _aB);   \
    const v2f _s = _aA + _aB;                                           \
    dstvar = _s.x + _s.y;                                               \
  } while (0)

#if HAVE_PLS
#define LOBCAST(val, dst) do { u2 _s = pls(val);                        \
    dst = __uint_as_float(loIsX ? _s.x : _s.y); } while (0)
#define HIBCAST(val, dst) do { u2 _s = pls(val);                        \
    dst = __uint_as_float(loIsX ? _s.y : _s.x); } while (0)
#else
#define LOBCAST(val, dst) dst = __uint_as_float((unsigned)              \
    __builtin_amdgcn_ds_bpermute(loaddr, (int)__float_as_uint(val)))
#define HIBCAST(val, dst) dst = __uint_as_float((unsigned)              \
    __builtin_amdgcn_ds_bpermute(hiaddr, (int)__float_as_uint(val)))
#endif

  // 4 per-lane staging slots (named regs; rotation by unroll-4)
  float xlA, xlB, xlC, xlD;
  LOADX(xlA, 0); LOADX(xlB, 1); LOADX(xlC, 2); LOADX(xlD, 3);

  float prex;                   // pipelined x-pre-activation for step t
  {
    v2f xu0[10];
    XBCAST(xlA, xu0);
    XDOT(xu0, prex);
  }

  // BODY(t): chain for step t; fillers = XBCAST+XDOT(t+1) + LOADX(t+4) + out
#define BODY(tcur, nslot, lslot) do {                                   \
    /* chain head: h-dot (2 interleaved trees of pk_fma) */             \
    v2f ahA = {ah0, 0.0f}, ahB = {0.0f, 0.0f};                          \
    _Pragma("unroll")                                                   \
    for (int _j = 0; _j < 5; ++_j)  ahA = vfma(sh2[_j], wh2[_j], ahA);  \
    _Pragma("unroll")                                                   \
    for (int _j = 5; _j < 10; ++_j) ahB = vfma(sh2[_j], wh2[_j], ahB);  \
    /* filler: next-step x broadcast + dot, next-next load */           \
    float prexN;                                                        \
    { v2f _xu[10];                                                      \
      XBCAST(nslot, _xu);                                               \
      XDOT(_xu, prexN); }                                               \
    { const int _tl = ((tcur) + 4 < TT) ? (tcur) + 4 : TT - 1;          \
      LOADX(lslot, _tl); }                                              \
    /* chain continues */                                               \
    const v2f ahv = ahA + ahB;                                          \
    const float preh = ahv.x + ahv.y;                                   \
    const float pre  = prex + preh;                                     \
    const float sig  = frcp(1.0f + fexp2(-pre));                        \
    const int zzi = __builtin_amdgcn_ds_bpermute(                       \
        zaddr, (int)__float_as_uint(sig));                              \
    float rr; LOBCAST(sig, rr);                                         \
    const float npre = fmaf(rr, preh, prex);                            \
    const float nn = fmaf(-2.0f, frcp(fexp2(npre) + 1.0f), 1.0f);       \
    float nh; HIBCAST(nn, nh);                                          \
    const float zz = __uint_as_float((unsigned)zzi);                    \
    h = fmaf(zz, h - nh, nh);                                           \
    /* refresh wave-uniform h (readlane pairs -> SGPRs) */              \
    _Pragma("unroll")                                                   \
    for (int _j = 0; _j < 9; ++_j) {                                    \
      sh2[_j].x = rlf(h, 2 * _j);                                       \
      sh2[_j].y = rlf(h, 2 * _j + 1);                                   \
    }                                                                   \
    sh2[9].x = rlf(h, 18); sh2[9].y = 0.0f;                             \
    /* out-projection (filler after the chain-critical readlanes) */    \
    v2f oA = {bo, 0.0f}, oB = {0.0f, 0.0f};                             \
    _Pragma("unroll")                                                   \
    for (int _j = 0; _j < 5; ++_j)  oA = vfma(sh2[_j], wo2[_j], oA);    \
    _Pragma("unroll")                                                   \
    for (int _j = 5; _j < 10; ++_j) oB = vfma(sh2[_j], wo2[_j], oB);    \
    const v2f ov = oA + oB;                                             \
    if (lane == 0) out[(size_t)(tcur) * NB + b] = ov.x + ov.y;          \
    prex = prexN;                                                       \
  } while (0)

  for (int t = 0; t < TT; t += 4) {
    BODY(t + 0, xlB, xlA);
    BODY(t + 1, xlC, xlB);
    BODY(t + 2, xlD, xlC);
    BODY(t + 3, xlA, xlD);
  }

#undef LOADX
#undef XBCAST
#undef XDOT
#undef BODY
#undef LOBCAST
#undef HIBCAST
}

extern "C" void kernel_launch(void* const* d_in, const int* in_sizes, int n_in,
                              void* d_out, int out_size, void* d_ws, size_t ws_size,
                              hipStream_t stream) {
  const float* x    = (const float*)d_in[0];
  const float* Wih  = (const float*)d_in[1];
  const float* Whh  = (const float*)d_in[2];
  const float* bih  = (const float*)d_in[3];
  const float* bhh  = (const float*)d_in[4];
  const float* Wout = (const float*)d_in[5];
  const float* bout = (const float*)d_in[6];
  float* out = (float*)d_out;

  gru57_v4<<<dim3(NB), dim3(64), 0, stream>>>(
      x, Wih, Whh, bih, bhh, Wout, bout, out);
}